// Round 6
// baseline (265.325 us; speedup 1.0000x reference)
//
#include <hip/hip_runtime.h>

// BiLSTM for MI355X (gfx950) — round 12 (resubmit; round-5 bench was an
// infrastructure acquisition timeout, no counters produced).
//  K1 gpre_gemm: byte-identical to R11 (pre-scaled f16-pair gpre, dwordx4 stores).
//  K2 lstm_scan: (a) single-accumulator matvec asm (16 chained fmacs, drops the
//     v0+v1 merge add, -1 VALU/step on a ~1.8us/instr kernel); (b) 64-thread
//     blocks (grid 4096) for finer dispatch packing — same total waves.
//  Fallback: unchanged R4 fused kernel if ws_size < 140 MB.

typedef __attribute__((ext_vector_type(8))) short short8;
typedef __attribute__((ext_vector_type(4))) float floatx4;

union F8 { uint32_t u[4]; short8 v; };
union H2 { uint32_t u; _Float16 h[2]; };
union B8 { uint4 q[2]; uint32_t d[8]; };

#define LDW  66  // fallback-kernel LDS stride (R4 layout, unchanged)
#define LDW2 68  // K1 stride: keeps all b128 LDS accesses 16B-aligned; 68%32=4

#define LOG2E 1.44269504088896340736f

__device__ __forceinline__ float tanh_fast(float x) {
    float e = __expf(-2.f * x);
    return __fdividef(2.f, 1.f + e) - 1.f;
}

// rotate v right by S within each row of 16 lanes (DPP row_ror:S)
#define ROT(v, S) __int_as_float(__builtin_amdgcn_mov_dpp(__float_as_int(v), 0x120 | (S), 0xf, 0xf, false))

// split f[0..7] (fp32) into truncated-bf16 hi and residual-bf16 lo fragments.
// Dword packing via v_perm_b32 — bit-exact vs (u0>>16)|(u1&0xFFFF0000).
__device__ __forceinline__ void split_pack(const float* f, uint32_t* hi, uint32_t* lo) {
#pragma unroll
    for (int i = 0; i < 4; ++i) {
        uint32_t u0 = __float_as_uint(f[2 * i]), u1 = __float_as_uint(f[2 * i + 1]);
        hi[i] = __builtin_amdgcn_perm(u1, u0, 0x07060302u);
        float r0 = f[2 * i]     - __uint_as_float(u0 & 0xFFFF0000u);
        float r1 = f[2 * i + 1] - __uint_as_float(u1 & 0xFFFF0000u);
        lo[i] = __builtin_amdgcn_perm(__float_as_uint(r1), __float_as_uint(r0), 0x07060302u);
    }
}

// ===================== K1: streaming gpre GEMM (f16-pair output, pre-scaled) =====================
// grid 1024 x 256. wave_id = blockIdx*4+wv handles rows [wave_id*256, +256) in 16 tiles.
// Output layout: dword index = (wave_id*16 + tile)*512 + j*8 + tp   (tp = step-pair 0..7)
__global__ __launch_bounds__(256, 2)
void gpre_gemm(const float* __restrict__ x,
               const float* __restrict__ W0, const float* __restrict__ b0,
               const float* __restrict__ Wf, const float* __restrict__ bf,
               uint32_t* __restrict__ gph)
{
    __shared__ __align__(16) float tA[4][16 * LDW2];  // xh transpose (wave-private)
    __shared__ __align__(16) float tB[4][16 * LDW2];  // gpre transpose (wave-private)

    const int tid  = threadIdx.x;
    const int wv   = tid >> 6;
    const int j    = tid & 63;
    const int nl   = j & 15;
    const int quad = j >> 4;

    // ---- B fragments (gathered once, used for 16 tiles)
    F8 B1h[4], B1l[4];
#pragma unroll
    for (int T = 0; T < 4; ++T) {
        float w[8];
#pragma unroll
        for (int e = 0; e < 8; ++e) {
            int k = quad * 8 + e;
            w[e] = (k < 20) ? W0[k * 64 + T * 16 + nl] : 0.f;
        }
        split_pack(w, B1h[T].u, B1l[T].u);
    }
    // Gate pre-scale folded into Wf / bf: gates [i|g|f|o], g gets -2log2e, others -log2e.
    F8 B2h[4][2], B2l[4][2];
#pragma unroll
    for (int T = 0; T < 4; ++T) {
        const float sgT = (T == 1) ? (-2.f * LOG2E) : (-LOG2E);
#pragma unroll
        for (int KH = 0; KH < 2; ++KH) {
            float w[8];
#pragma unroll
            for (int e = 0; e < 8; ++e) {
                int k = KH * 32 + quad * 8 + e;
                w[e] = Wf[k * 64 + T * 16 + nl] * sgT;
            }
            split_pack(w, B2h[T][KH].u, B2l[T][KH].u);
        }
    }

    float b0v[4], bfv[4];
#pragma unroll
    for (int T = 0; T < 4; ++T) {
        const float sgT = (T == 1) ? (-2.f * LOG2E) : (-LOG2E);
        b0v[T] = b0[T * 16 + nl];
        bfv[T] = (bf[T * 16 + nl] + ((T == 2) ? 1.f : 0.f)) * sgT;  // fold haiku forget +1, then scale
    }

    const size_t base = (size_t)(blockIdx.x * 4 + wv) * 256;

    // ---- x prefetch (1 tile deep). Lane (quad,nl) needs x[r+nl][quad*8 .. +7].
    float4 xp0, xp1;
    {
        const float* xr = x + (base + nl) * 20;
        if (quad < 2) {
            xp0 = *(const float4*)(xr + quad * 8);
            xp1 = *(const float4*)(xr + quad * 8 + 4);
        } else if (quad == 2) {
            xp0 = *(const float4*)(xr + 16);
            xp1 = (float4){0.f, 0.f, 0.f, 0.f};
        } else {
            xp0 = (float4){0.f, 0.f, 0.f, 0.f};
            xp1 = (float4){0.f, 0.f, 0.f, 0.f};
        }
    }

#pragma unroll 1
    for (int tile = 0; tile < 16; ++tile) {
        float xk[8] = {xp0.x, xp0.y, xp0.z, xp0.w, xp1.x, xp1.y, xp1.z, xp1.w};

        // prefetch next tile's x
        {
            int tn = (tile < 15) ? (tile + 1) : 15;
            const float* xr = x + (base + tn * 16 + nl) * 20;
            if (quad < 2) {
                xp0 = *(const float4*)(xr + quad * 8);
                xp1 = *(const float4*)(xr + quad * 8 + 4);
            } else if (quad == 2) {
                xp0 = *(const float4*)(xr + 16);
            }
        }

        F8 A1h, A1l;
        split_pack(xk, A1h.u, A1l.u);

        floatx4 acc1[4];
#pragma unroll
        for (int T = 0; T < 4; ++T) acc1[T] = (floatx4){b0v[T], b0v[T], b0v[T], b0v[T]};
#pragma unroll
        for (int T = 0; T < 4; ++T) {
            acc1[T] = __builtin_amdgcn_mfma_f32_16x16x32_bf16(A1h.v, B1h[T].v, acc1[T], 0, 0, 0);
            acc1[T] = __builtin_amdgcn_mfma_f32_16x16x32_bf16(A1l.v, B1h[T].v, acc1[T], 0, 0, 0);
            acc1[T] = __builtin_amdgcn_mfma_f32_16x16x32_bf16(A1h.v, B1l[T].v, acc1[T], 0, 0, 0);
        }

        // relu + transpose (C-layout -> [tau][e])
#pragma unroll
        for (int T = 0; T < 4; ++T)
#pragma unroll
            for (int reg = 0; reg < 4; ++reg)
                tA[wv][(quad * 4 + reg) * LDW2 + T * 16 + nl] = fmaxf(acc1[T][reg], 0.f);
        __builtin_amdgcn_wave_barrier();

        F8 A2h[2], A2l[2];
#pragma unroll
        for (int KH = 0; KH < 2; ++KH) {
            float xe[8];
#pragma unroll
            for (int e = 0; e < 8; ++e)
                xe[e] = tA[wv][nl * LDW2 + KH * 32 + quad * 8 + e];
            split_pack(xe, A2h[KH].u, A2l[KH].u);
        }

        floatx4 acc2[4];
#pragma unroll
        for (int T = 0; T < 4; ++T) acc2[T] = (floatx4){bfv[T], bfv[T], bfv[T], bfv[T]};
#pragma unroll
        for (int T = 0; T < 4; ++T)
#pragma unroll
            for (int KH = 0; KH < 2; ++KH) {
                acc2[T] = __builtin_amdgcn_mfma_f32_16x16x32_bf16(A2h[KH].v, B2h[T][KH].v, acc2[T], 0, 0, 0);
                acc2[T] = __builtin_amdgcn_mfma_f32_16x16x32_bf16(A2l[KH].v, B2h[T][KH].v, acc2[T], 0, 0, 0);
                acc2[T] = __builtin_amdgcn_mfma_f32_16x16x32_bf16(A2h[KH].v, B2l[T][KH].v, acc2[T], 0, 0, 0);
            }

        // gpre transpose -> [tau][gate] rows in LDS
#pragma unroll
        for (int T = 0; T < 4; ++T)
#pragma unroll
            for (int reg = 0; reg < 4; ++reg)
                tB[wv][(quad * 4 + reg) * LDW2 + T * 16 + nl] = acc2[T][reg];
        __builtin_amdgcn_wave_barrier();

        // pack step-pairs (2tp, 2tp+1) to f16x2 (RNE); per-lane-contiguous 32B store
        {
            B8 r;
#pragma unroll
            for (int tp = 0; tp < 8; ++tp) {
                float a0 = tB[wv][(2 * tp) * LDW2 + j];
                float a1 = tB[wv][(2 * tp + 1) * LDW2 + j];
                H2 pk;
                pk.h[0] = (_Float16)a0;   // v_cvt_f16_f32 (RNE)
                pk.h[1] = (_Float16)a1;
                r.d[tp] = pk.u;
            }
            uint32_t* gp = gph + ((size_t)(blockIdx.x * 4 + wv) * 16 + tile) * 512 + j * 8;
            *(uint4*)(gp)     = r.q[0];
            *(uint4*)(gp + 4) = r.q[1];
        }
        __builtin_amdgcn_wave_barrier();   // protect tA/tB reuse next tile
    }
}

// ===================== K2: serial scan + epilogue =====================
// R12: 64-thread blocks (1 wave = 1 batch); single-accumulator matvec asm.
__global__ __launch_bounds__(64, 4)
void lstm_scan(const uint32_t* __restrict__ gph,
               const float* __restrict__ x,
               const float* __restrict__ W0, const float* __restrict__ b0,
               const float* __restrict__ Wf,
               const float* __restrict__ Wb, const float* __restrict__ bb,
               const float* __restrict__ W1, const float* __restrict__ b1,
               const float* __restrict__ W2, const float* __restrict__ b2,
               const float* __restrict__ W3, const float* __restrict__ b3,
               float* __restrict__ out)
{
    __shared__ __align__(16) float xh_sh[64];
    __shared__ __align__(16) float h_sh[48];   // [0:16) hf, [16:32) hb, [32:48) l2

    const int j    = threadIdx.x;
    const int b    = blockIdx.x;
    const int nl   = j & 15;
    const int quad = j >> 4;

    int rot1 = __builtin_amdgcn_mov_dpp(j, 0x121, 0xf, 0xf, false);
    const bool plus = ((rot1 & 15) == ((nl + 1) & 15));

    // recurrent weights, pre-scaled by the gate's exp2 factor (matches K1's gpre scale)
    const float sj = (quad == 1) ? (-2.f * LOG2E) : (-LOG2E);
    float wfhp[16];
#pragma unroll
    for (int s = 0; s < 16; ++s) {
        const int srcq = plus ? ((nl + s) & 15) : ((nl + 16 - s) & 15);
        wfhp[s] = Wf[(64 + srcq) * 64 + j] * sj;
    }

    // scan-loop activation constants:
    //  q0,2,3: a = sigmoid = rcp(1+e)              -> amul=1, aadd=0
    //  q1:     a = -2log2e * tanh(g) = amul*y+aadd -> amul=-4log2e, aadd=+2log2e
    const float amul = (quad == 1) ? (-4.f * LOG2E) : 1.f;
    const float aadd = (quad == 1) ? ( 2.f * LOG2E) : 0.f;

    // epilogue (bwd step) constants — original unscaled forms
    const float gmulE = (quad == 1) ? -2.f : -1.f;
    const float amulE = (quad == 1) ? 2.f : 1.f;
    const float aaddE = (quad == 1) ? -1.f : 0.f;

    // bpermute byte-addresses for gathering i/g/f/o of unit nl (hoisted)
    const int adr_i = 4 * nl;
    const int adr_g = 4 * nl + 64;
    const int adr_f = 4 * nl + 128;
    const int adr_o = 4 * nl + 192;

    float C = 0.f, hh = 0.f;   // C = -2log2e * c
    const uint32_t* gb = gph + (size_t)b * 8192;   // 16 blocks x 512 dwords

    // one LSTM step given pre-scaled gate pre-activation G.
    // Single 16-deep fmac chain (issue-bound regime: -1 instr beats +chain).
#define STEPG(G)                                                               \
    {                                                                          \
        float v0 = (G);                                                        \
        asm volatile(                                                          \
            "v_fmac_f32 %0, %1, %2\n\t"                                        \
            "s_nop 1\n\t"                                                      \
            "v_fmac_f32_dpp %0, %1, %3 row_ror:1 row_mask:0xf bank_mask:0xf\n\t"  \
            "v_fmac_f32_dpp %0, %1, %4 row_ror:2 row_mask:0xf bank_mask:0xf\n\t"  \
            "v_fmac_f32_dpp %0, %1, %5 row_ror:3 row_mask:0xf bank_mask:0xf\n\t"  \
            "v_fmac_f32_dpp %0, %1, %6 row_ror:4 row_mask:0xf bank_mask:0xf\n\t"  \
            "v_fmac_f32_dpp %0, %1, %7 row_ror:5 row_mask:0xf bank_mask:0xf\n\t"  \
            "v_fmac_f32_dpp %0, %1, %8 row_ror:6 row_mask:0xf bank_mask:0xf\n\t"  \
            "v_fmac_f32_dpp %0, %1, %9 row_ror:7 row_mask:0xf bank_mask:0xf\n\t"  \
            "v_fmac_f32_dpp %0, %1, %10 row_ror:8 row_mask:0xf bank_mask:0xf\n\t" \
            "v_fmac_f32_dpp %0, %1, %11 row_ror:9 row_mask:0xf bank_mask:0xf\n\t" \
            "v_fmac_f32_dpp %0, %1, %12 row_ror:10 row_mask:0xf bank_mask:0xf\n\t" \
            "v_fmac_f32_dpp %0, %1, %13 row_ror:11 row_mask:0xf bank_mask:0xf\n\t" \
            "v_fmac_f32_dpp %0, %1, %14 row_ror:12 row_mask:0xf bank_mask:0xf\n\t" \
            "v_fmac_f32_dpp %0, %1, %15 row_ror:13 row_mask:0xf bank_mask:0xf\n\t" \
            "v_fmac_f32_dpp %0, %1, %16 row_ror:14 row_mask:0xf bank_mask:0xf\n\t" \
            "v_fmac_f32_dpp %0, %1, %17 row_ror:15 row_mask:0xf bank_mask:0xf"    \
            : "+&v"(v0)                                                        \
            : "v"(hh),                                                         \
              "v"(wfhp[0]),  "v"(wfhp[1]),  "v"(wfhp[2]),  "v"(wfhp[3]),       \
              "v"(wfhp[4]),  "v"(wfhp[5]),  "v"(wfhp[6]),  "v"(wfhp[7]),       \
              "v"(wfhp[8]),  "v"(wfhp[9]),  "v"(wfhp[10]), "v"(wfhp[11]),      \
              "v"(wfhp[12]), "v"(wfhp[13]), "v"(wfhp[14]), "v"(wfhp[15]));     \
        float e = __builtin_amdgcn_exp2f(v0);                                  \
        float y = __builtin_amdgcn_rcpf(1.f + e);                              \
        float a = fmaf(y, amul, aadd);                                         \
        int ab = __float_as_int(a);                                            \
        float ai = __int_as_float(__builtin_amdgcn_ds_bpermute(adr_i, ab));    \
        float ag = __int_as_float(__builtin_amdgcn_ds_bpermute(adr_g, ab));    \
        float af = __int_as_float(__builtin_amdgcn_ds_bpermute(adr_f, ab));    \
        float ao = __int_as_float(__builtin_amdgcn_ds_bpermute(adr_o, ab));    \
        C = fmaf(af, C, ai * ag);                                              \
        float e2 = __builtin_amdgcn_exp2f(C);                                  \
        float th = fmaf(__builtin_amdgcn_rcpf(1.f + e2), 2.f, -1.f);           \
        hh = ao * th;                                                          \
    }

    // parity double-buffered blocks: 16 blocks x 8 dwords (= 16 steps each)
    B8 bufA, bufB;
    bufA.q[0] = *(const uint4*)(gb + j * 8);
    bufA.q[1] = *(const uint4*)(gb + j * 8 + 4);
    bufB.q[0] = *(const uint4*)(gb + 512 + j * 8);
    bufB.q[1] = *(const uint4*)(gb + 512 + j * 8 + 4);

#pragma unroll 1
    for (int blk = 0; blk < 16; blk += 2) {
#pragma unroll
        for (int p = 0; p < 8; ++p) {
            H2 u; u.u = bufA.d[p];
            float g0 = (float)u.h[0];
            float g1 = (float)u.h[1];
            STEPG(g0)
            STEPG(g1)
        }
        {
            int nb = blk + 2; nb = (nb > 15) ? 15 : nb;   // uniform clamp
            bufA.q[0] = *(const uint4*)(gb + nb * 512 + j * 8);
            bufA.q[1] = *(const uint4*)(gb + nb * 512 + j * 8 + 4);
        }
#pragma unroll
        for (int p = 0; p < 8; ++p) {
            H2 u; u.u = bufB.d[p];
            float g0 = (float)u.h[0];
            float g1 = (float)u.h[1];
            STEPG(g0)
            STEPG(g1)
        }
        {
            int nb = blk + 3; nb = (nb > 15) ? 15 : nb;
            bufB.q[0] = *(const uint4*)(gb + nb * 512 + j * 8);
            bufB.q[1] = *(const uint4*)(gb + nb * 512 + j * 8 + 4);
        }
    }
#undef STEPG

    // epilogue: recompute xh[255] exactly from x
    {
        const float* xr = x + (size_t)b * (256 * 20) + 255 * 20;
        float s = b0[j];
#pragma unroll
        for (int k = 0; k < 20; ++k) s = fmaf(xr[k], W0[k * 64 + j], s);
        xh_sh[j] = fmaxf(s, 0.f);
        if (j < 16) h_sh[j] = hh;
    }
    __builtin_amdgcn_wave_barrier();

    // bwd LSTM single step from zero state (original constants)
    {
        float u0 = bb[j], u1 = 0.f, u2 = 0.f, u3 = 0.f;
        const float* xr = xh_sh;
#pragma unroll
        for (int k4 = 0; k4 < 16; ++k4) {
            u0 = fmaf(xr[4 * k4 + 0], Wb[(4 * k4 + 0) * 64 + j], u0);
            u1 = fmaf(xr[4 * k4 + 1], Wb[(4 * k4 + 1) * 64 + j], u1);
            u2 = fmaf(xr[4 * k4 + 2], Wb[(4 * k4 + 2) * 64 + j], u2);
            u3 = fmaf(xr[4 * k4 + 3], Wb[(4 * k4 + 3) * 64 + j], u3);
        }
        float gated = (u0 + u1) + (u2 + u3);
        float e = __expf(gmulE * gated);
        float y = __fdividef(1.f, 1.f + e);
        float a = fmaf(y, amulE, aaddE);
        float ai = __shfl(a, nl, 64);
        float ag = __shfl(a, nl + 16, 64);
        float ao = __shfl(a, nl + 48, 64);
        float cb = ai * ag;
        float hb = ao * tanh_fast(cb);
        __builtin_amdgcn_wave_barrier();
        if (j < 16) h_sh[16 + j] = hb;
        __builtin_amdgcn_wave_barrier();
    }

    // head MLP
    {
        float u0 = b1[j], u1 = 0.f, u2 = 0.f, u3 = 0.f;
        const float4* hs = (const float4*)h_sh;
#pragma unroll
        for (int k4 = 0; k4 < 8; ++k4) {
            float4 v = hs[k4];
            u0 = fmaf(v.x, W1[(4 * k4 + 0) * 64 + j], u0);
            u1 = fmaf(v.y, W1[(4 * k4 + 1) * 64 + j], u1);
            u2 = fmaf(v.z, W1[(4 * k4 + 2) * 64 + j], u2);
            u3 = fmaf(v.w, W1[(4 * k4 + 3) * 64 + j], u3);
        }
        float l1 = fmaxf((u0 + u1) + (u2 + u3), 0.f);
        __builtin_amdgcn_wave_barrier();
        xh_sh[j] = l1;
        __builtin_amdgcn_wave_barrier();

        if (j < 16) {
            float v0 = b2[j], v1 = 0.f, v2 = 0.f, v3 = 0.f;
            const float4* ls = (const float4*)xh_sh;
#pragma unroll
            for (int k4 = 0; k4 < 16; ++k4) {
                float4 v = ls[k4];
                v0 = fmaf(v.x, W2[(4 * k4 + 0) * 16 + j], v0);
                v1 = fmaf(v.y, W2[(4 * k4 + 1) * 16 + j], v1);
                v2 = fmaf(v.z, W2[(4 * k4 + 2) * 16 + j], v2);
                v3 = fmaf(v.w, W2[(4 * k4 + 3) * 16 + j], v3);
            }
            h_sh[32 + j] = fmaxf((v0 + v1) + (v2 + v3), 0.f);
        }
        __builtin_amdgcn_wave_barrier();

        if (j < 2) {
            float o = b3[j];
#pragma unroll
            for (int k = 0; k < 16; ++k)
                o = fmaf(h_sh[32 + k], W3[k * 2 + j], o);
            out[b * 2 + j] = o;
        }
    }
}

// ===================== fallback: unchanged R4 fused kernel =====================
__global__ __launch_bounds__(64, 2)
void bilstm_fused_r4(const float* __restrict__ x,
                     const float* __restrict__ W0, const float* __restrict__ b0,
                     const float* __restrict__ Wf, const float* __restrict__ bf,
                     const float* __restrict__ Wb, const float* __restrict__ bb,
                     const float* __restrict__ W1, const float* __restrict__ b1,
                     const float* __restrict__ W2, const float* __restrict__ b2,
                     const float* __restrict__ W3, const float* __restrict__ b3,
                     float* __restrict__ out)
{
    __shared__ __align__(16) float lds_xh[16 * LDW];
    __shared__ __align__(16) float lds_g [16 * LDW];
    __shared__ __align__(16) float h_sh[48];

    const int j    = threadIdx.x;
    const int b    = blockIdx.x;
    const int nl   = j & 15;
    const int quad = j >> 4;

    int rot1 = __builtin_amdgcn_mov_dpp(j, 0x121, 0xf, 0xf, false);
    const bool plus = ((rot1 & 15) == ((nl + 1) & 15));

    float wfhp[16];
#pragma unroll
    for (int s = 0; s < 16; ++s) {
        const int srcq = plus ? ((nl + s) & 15) : ((nl + 16 - s) & 15);
        wfhp[s] = Wf[(64 + srcq) * 64 + j];
    }

    F8 B1h[4], B1l[4];
#pragma unroll
    for (int T = 0; T < 4; ++T) {
        float w[8];
#pragma unroll
        for (int e = 0; e < 8; ++e) {
            int k = quad * 8 + e;
            w[e] = (k < 20) ? W0[k * 64 + T * 16 + nl] : 0.f;
        }
        split_pack(w, B1h[T].u, B1l[T].u);
    }
    F8 B2h[4][2], B2l[4][2];
#pragma unroll
    for (int T = 0; T < 4; ++T)
#pragma unroll
        for (int KH = 0; KH < 2; ++KH) {
            float w[8];
#pragma unroll
            for (int e = 0; e < 8; ++e) {
                int k = KH * 32 + quad * 8 + e;
                w[e] = Wf[k * 64 + T * 16 + nl];
            }
            split_pack(w, B2h[T][KH].u, B2l[T][KH].u);
        }

    float b0v[4], bfv[4];
#pragma unroll
    for (int T = 0; T < 4; ++T) {
        b0v[T] = b0[T * 16 + nl];
        bfv[T] = bf[T * 16 + nl];
    }

    const float gmul  = (quad == 1) ? -2.f : -1.f;
    const float gbias = (quad == 2) ? 1.f : 0.f;
    const float amul  = (quad == 1) ? 2.f : 1.f;
    const float aadd  = (quad == 1) ? -1.f : 0.f;
    const bool  b0sel = (quad & 1) != 0;
    const bool  b1sel = (quad & 2) != 0;

    float c = 0.f, hh = 0.f;
    const float* xb = x + (size_t)b * (256 * 20);

#pragma unroll 1
    for (int ch = 0; ch < 16; ++ch) {
        const int t0 = ch * 16;
        const float* xrow = xb + (size_t)(t0 + nl) * 20;
        float xk[8];
#pragma unroll
        for (int e = 0; e < 8; ++e) {
            int k = quad * 8 + e;
            xk[e] = (k < 20) ? xrow[k] : 0.f;
        }
        F8 A1h, A1l;
        split_pack(xk, A1h.u, A1l.u);

        floatx4 acc1[4];
#pragma unroll
        for (int T = 0; T < 4; ++T) acc1[T] = (floatx4){b0v[T], b0v[T], b0v[T], b0v[T]};
#pragma unroll
        for (int T = 0; T < 4; ++T) {
            acc1[T] = __builtin_amdgcn_mfma_f32_16x16x32_bf16(A1h.v, B1h[T].v, acc1[T], 0, 0, 0);
            acc1[T] = __builtin_amdgcn_mfma_f32_16x16x32_bf16(A1l.v, B1h[T].v, acc1[T], 0, 0, 0);
            acc1[T] = __builtin_amdgcn_mfma_f32_16x16x32_bf16(A1h.v, B1l[T].v, acc1[T], 0, 0, 0);
        }
#pragma unroll
        for (int T = 0; T < 4; ++T)
#pragma unroll
            for (int reg = 0; reg < 4; ++reg)
                lds_xh[(quad * 4 + reg) * LDW + T * 16 + nl] = fmaxf(acc1[T][reg], 0.f);
        __builtin_amdgcn_wave_barrier();

        F8 A2h[2], A2l[2];
#pragma unroll
        for (int KH = 0; KH < 2; ++KH) {
            float xe[8];
#pragma unroll
            for (int e = 0; e < 8; ++e)
                xe[e] = lds_xh[nl * LDW + KH * 32 + quad * 8 + e];
            split_pack(xe, A2h[KH].u, A2l[KH].u);
        }

        floatx4 acc2[4];
#pragma unroll
        for (int T = 0; T < 4; ++T) acc2[T] = (floatx4){bfv[T], bfv[T], bfv[T], bfv[T]};
#pragma unroll
        for (int T = 0; T < 4; ++T)
#pragma unroll
            for (int KH = 0; KH < 2; ++KH) {
                acc2[T] = __builtin_amdgcn_mfma_f32_16x16x32_bf16(A2h[KH].v, B2h[T][KH].v, acc2[T], 0, 0, 0);
                acc2[T] = __builtin_amdgcn_mfma_f32_16x16x32_bf16(A2l[KH].v, B2h[T][KH].v, acc2[T], 0, 0, 0);
                acc2[T] = __builtin_amdgcn_mfma_f32_16x16x32_bf16(A2h[KH].v, B2l[T][KH].v, acc2[T], 0, 0, 0);
            }
#pragma unroll
        for (int T = 0; T < 4; ++T)
#pragma unroll
            for (int reg = 0; reg < 4; ++reg)
                lds_g[(quad * 4 + reg) * LDW + T * 16 + nl] = acc2[T][reg];
        __builtin_amdgcn_wave_barrier();

        float gcur = lds_g[j];
#pragma unroll
        for (int tau = 0; tau < 16; ++tau) {
            float gnext = lds_g[((tau < 15) ? (tau + 1) : 15) * LDW + j];
            float v0 = hh * wfhp[0];
            float v1 = ROT(hh, 1) * wfhp[1];
            float v2 = ROT(hh, 2) * wfhp[2];
            float v3 = ROT(hh, 3) * wfhp[3];
            v0 = fmaf(ROT(hh, 4),  wfhp[4],  v0);
            v1 = fmaf(ROT(hh, 5),  wfhp[5],  v1);
            v2 = fmaf(ROT(hh, 6),  wfhp[6],  v2);
            v3 = fmaf(ROT(hh, 7),  wfhp[7],  v3);
            v0 = fmaf(ROT(hh, 8),  wfhp[8],  v0);
            v1 = fmaf(ROT(hh, 9),  wfhp[9],  v1);
            v2 = fmaf(ROT(hh, 10), wfhp[10], v2);
            v3 = fmaf(ROT(hh, 11), wfhp[11], v3);
            v0 = fmaf(ROT(hh, 12), wfhp[12], v0);
            v1 = fmaf(ROT(hh, 13), wfhp[13], v1);
            v2 = fmaf(ROT(hh, 14), wfhp[14], v2);
            v3 = fmaf(ROT(hh, 15), wfhp[15], v3);
            float gated = gcur + ((v0 + v1) + (v2 + v3));

            float e = __expf(gmul * (gated + gbias));
            float y = __fdividef(1.f, 1.f + e);
            float a = fmaf(y, amul, aadd);

            float d1 = __shfl_xor(a, 16);
            float d2 = __shfl_xor(a, 32);
            float d3 = __shfl_xor(a, 48);
            float lo  = b0sel ? d1 : a;
            float hi  = b0sel ? d3 : d2;
            float lo1 = b0sel ? a  : d1;
            float hi1 = b0sel ? d2 : d3;
            float ai = b1sel ? hi  : lo;
            float ag = b1sel ? hi1 : lo1;
            float af = b1sel ? lo  : hi;
            float ao = b1sel ? lo1 : hi1;

            c  = fmaf(af, c, ai * ag);
            hh = ao * tanh_fast(c);
            gcur = gnext;
        }
    }

    if (j < 16) h_sh[j] = hh;
    __builtin_amdgcn_wave_barrier();

    {
        float u0 = bb[j], u1 = 0.f, u2 = 0.f, u3 = 0.f;
        const float* xr = &lds_xh[15 * LDW];
#pragma unroll
        for (int k4 = 0; k4 < 16; ++k4) {
            u0 = fmaf(xr[4 * k4 + 0], Wb[(4 * k4 + 0) * 64 + j], u0);
            u1 = fmaf(xr[4 * k4 + 1], Wb[(4 * k4 + 1) * 64 + j], u1);
            u2 = fmaf(xr[4 * k4 + 2], Wb[(4 * k4 + 2) * 64 + j], u2);
            u3 = fmaf(xr[4 * k4 + 3], Wb[(4 * k4 + 3) * 64 + j], u3);
        }
        float gated = (u0 + u1) + (u2 + u3);
        float e = __expf(gmul * gated);
        float y = __fdividef(1.f, 1.f + e);
        float a = fmaf(y, amul, aadd);
        float ai = __shfl(a, nl, 64);
        float ag = __shfl(a, nl + 16, 64);
        float ao = __shfl(a, nl + 48, 64);
        float cb = ai * ag;
        float hb = ao * tanh_fast(cb);
        __builtin_amdgcn_wave_barrier();
        if (j < 16) h_sh[16 + j] = hb;
        __builtin_amdgcn_wave_barrier();
    }

    {
        float u0 = b1[j], u1 = 0.f, u2 = 0.f, u3 = 0.f;
        const float4* hs = (const float4*)h_sh;
#pragma unroll
        for (int k4 = 0; k4 < 8; ++k4) {
            float4 v = hs[k4];
            u0 = fmaf(v.x, W1[(4 * k4 + 0) * 64 + j], u0);
            u1 = fmaf(v.y, W1[(4 * k4 + 1) * 64 + j], u1);
            u2 = fmaf(v.z, W1[(4 * k4 + 2) * 64 + j], u2);
            u3 = fmaf(v.w, W1[(4 * k4 + 3) * 64 + j], u3);
        }
        float l1 = fmaxf((u0 + u1) + (u2 + u3), 0.f);
        __builtin_amdgcn_wave_barrier();
        lds_g[j] = l1;
        __builtin_amdgcn_wave_barrier();

        if (j < 16) {
            float v0 = b2[j], v1 = 0.f, v2 = 0.f, v3 = 0.f;
            const float4* ls = (const float4*)lds_g;
#pragma unroll
            for (int k4 = 0; k4 < 16; ++k4) {
                float4 v = ls[k4];
                v0 = fmaf(v.x, W2[(4 * k4 + 0) * 16 + j], v0);
                v1 = fmaf(v.y, W2[(4 * k4 + 1) * 16 + j], v1);
                v2 = fmaf(v.z, W2[(4 * k4 + 2) * 16 + j], v2);
                v3 = fmaf(v.w, W2[(4 * k4 + 3) * 16 + j], v3);
            }
            h_sh[32 + j] = fmaxf((v0 + v1) + (v2 + v3), 0.f);
        }
        __builtin_amdgcn_wave_barrier();

        if (j < 2) {
            float o = b3[j];
#pragma unroll
            for (int k = 0; k < 16; ++k)
                o = fmaf(h_sh[32 + k], W3[k * 2 + j], o);
            out[b * 2 + j] = o;
        }
    }
}

extern "C" void kernel_launch(void* const* d_in, const int* in_sizes, int n_in,
                              void* d_out, int out_size, void* d_ws, size_t ws_size,
                              hipStream_t stream) {
    const float* x  = (const float*)d_in[0];
    const float* W0 = (const float*)d_in[1];
    const float* b0 = (const float*)d_in[2];
    const float* Wf = (const float*)d_in[3];
    const float* bf = (const float*)d_in[4];
    const float* Wb = (const float*)d_in[5];
    const float* bb = (const float*)d_in[6];
    const float* W1 = (const float*)d_in[7];
    const float* b1 = (const float*)d_in[8];
    const float* W2 = (const float*)d_in[9];
    const float* b2 = (const float*)d_in[10];
    const float* W3 = (const float*)d_in[11];
    const float* b3 = (const float*)d_in[12];
    float* outp = (float*)d_out;

    const size_t need = (size_t)4096 * 128 * 64 * sizeof(uint32_t);  // 134 MB (f16 pairs)
    if (ws_size >= need) {
        uint32_t* gph = (uint32_t*)d_ws;
        hipLaunchKernelGGL(gpre_gemm, dim3(1024), dim3(256), 0, stream,
                           x, W0, b0, Wf, bf, gph);
        hipLaunchKernelGGL(lstm_scan, dim3(4096), dim3(64), 0, stream,
                           gph, x, W0, b0, Wf, Wb, bb, W1, b1, W2, b2, W3, b3, outp);
    } else {
        hipLaunchKernelGGL(bilstm_fused_r4, dim3(4096), dim3(64), 0, stream,
                           x, W0, b0, Wf, bf, Wb, bb, W1, b1, W2, b2, W3, b3, outp);
    }
}

// Round 13
// 254.014 us; speedup vs baseline: 1.0445x; 1.0445x over previous
//
#include <hip/hip_runtime.h>

// BiLSTM for MI355X (gfx950) — round 13 (sixth resubmit; rounds 7-12 all
// failed with GPUAcquisitionTimeout — broker capacity, no counters produced).
// Revert K2 to the R11-verified structure (256-thread blocks, 2-accumulator
// DPP matvec). R12's single-acc chain + 64-thread blocks regressed
// 83.2 -> 91.6 us (latency exposure + occupancy loss; VALUBusy 73->62,
// Occupancy 31->26.7).
//  K1 gpre_gemm: unchanged (pre-scaled f16-pair gpre, dwordx4 stores).
//  K2 lstm_scan: R11-exact — pre-scaled gpre -> exp2 direct; C = -2log2e*c
//     carried; 2-accumulator asm matvec (dep distance 2); dwordx4 refills.
//  Fallback: unchanged R4 fused kernel if ws_size < 140 MB.

typedef __attribute__((ext_vector_type(8))) short short8;
typedef __attribute__((ext_vector_type(4))) float floatx4;

union F8 { uint32_t u[4]; short8 v; };
union H2 { uint32_t u; _Float16 h[2]; };
union B8 { uint4 q[2]; uint32_t d[8]; };

#define LDW  66  // fallback-kernel LDS stride (R4 layout, unchanged)
#define LDW2 68  // K1 stride: keeps all b128 LDS accesses 16B-aligned; 68%32=4

#define LOG2E 1.44269504088896340736f

__device__ __forceinline__ float tanh_fast(float x) {
    float e = __expf(-2.f * x);
    return __fdividef(2.f, 1.f + e) - 1.f;
}

// rotate v right by S within each row of 16 lanes (DPP row_ror:S)
#define ROT(v, S) __int_as_float(__builtin_amdgcn_mov_dpp(__float_as_int(v), 0x120 | (S), 0xf, 0xf, false))

// split f[0..7] (fp32) into truncated-bf16 hi and residual-bf16 lo fragments.
// Dword packing via v_perm_b32 — bit-exact vs (u0>>16)|(u1&0xFFFF0000).
__device__ __forceinline__ void split_pack(const float* f, uint32_t* hi, uint32_t* lo) {
#pragma unroll
    for (int i = 0; i < 4; ++i) {
        uint32_t u0 = __float_as_uint(f[2 * i]), u1 = __float_as_uint(f[2 * i + 1]);
        hi[i] = __builtin_amdgcn_perm(u1, u0, 0x07060302u);
        float r0 = f[2 * i]     - __uint_as_float(u0 & 0xFFFF0000u);
        float r1 = f[2 * i + 1] - __uint_as_float(u1 & 0xFFFF0000u);
        lo[i] = __builtin_amdgcn_perm(__float_as_uint(r1), __float_as_uint(r0), 0x07060302u);
    }
}

// ===================== K1: streaming gpre GEMM (f16-pair output, pre-scaled) =====================
// grid 1024 x 256. wave_id = blockIdx*4+wv handles rows [wave_id*256, +256) in 16 tiles.
// Output layout: dword index = (wave_id*16 + tile)*512 + j*8 + tp   (tp = step-pair 0..7)
__global__ __launch_bounds__(256, 2)
void gpre_gemm(const float* __restrict__ x,
               const float* __restrict__ W0, const float* __restrict__ b0,
               const float* __restrict__ Wf, const float* __restrict__ bf,
               uint32_t* __restrict__ gph)
{
    __shared__ __align__(16) float tA[4][16 * LDW2];  // xh transpose (wave-private)
    __shared__ __align__(16) float tB[4][16 * LDW2];  // gpre transpose (wave-private)

    const int tid  = threadIdx.x;
    const int wv   = tid >> 6;
    const int j    = tid & 63;
    const int nl   = j & 15;
    const int quad = j >> 4;

    // ---- B fragments (gathered once, used for 16 tiles)
    F8 B1h[4], B1l[4];
#pragma unroll
    for (int T = 0; T < 4; ++T) {
        float w[8];
#pragma unroll
        for (int e = 0; e < 8; ++e) {
            int k = quad * 8 + e;
            w[e] = (k < 20) ? W0[k * 64 + T * 16 + nl] : 0.f;
        }
        split_pack(w, B1h[T].u, B1l[T].u);
    }
    // Gate pre-scale folded into Wf / bf: gates [i|g|f|o], g gets -2log2e, others -log2e.
    F8 B2h[4][2], B2l[4][2];
#pragma unroll
    for (int T = 0; T < 4; ++T) {
        const float sgT = (T == 1) ? (-2.f * LOG2E) : (-LOG2E);
#pragma unroll
        for (int KH = 0; KH < 2; ++KH) {
            float w[8];
#pragma unroll
            for (int e = 0; e < 8; ++e) {
                int k = KH * 32 + quad * 8 + e;
                w[e] = Wf[k * 64 + T * 16 + nl] * sgT;
            }
            split_pack(w, B2h[T][KH].u, B2l[T][KH].u);
        }
    }

    float b0v[4], bfv[4];
#pragma unroll
    for (int T = 0; T < 4; ++T) {
        const float sgT = (T == 1) ? (-2.f * LOG2E) : (-LOG2E);
        b0v[T] = b0[T * 16 + nl];
        bfv[T] = (bf[T * 16 + nl] + ((T == 2) ? 1.f : 0.f)) * sgT;  // fold haiku forget +1, then scale
    }

    const size_t base = (size_t)(blockIdx.x * 4 + wv) * 256;

    // ---- x prefetch (1 tile deep). Lane (quad,nl) needs x[r+nl][quad*8 .. +7].
    float4 xp0, xp1;
    {
        const float* xr = x + (base + nl) * 20;
        if (quad < 2) {
            xp0 = *(const float4*)(xr + quad * 8);
            xp1 = *(const float4*)(xr + quad * 8 + 4);
        } else if (quad == 2) {
            xp0 = *(const float4*)(xr + 16);
            xp1 = (float4){0.f, 0.f, 0.f, 0.f};
        } else {
            xp0 = (float4){0.f, 0.f, 0.f, 0.f};
            xp1 = (float4){0.f, 0.f, 0.f, 0.f};
        }
    }

#pragma unroll 1
    for (int tile = 0; tile < 16; ++tile) {
        float xk[8] = {xp0.x, xp0.y, xp0.z, xp0.w, xp1.x, xp1.y, xp1.z, xp1.w};

        // prefetch next tile's x
        {
            int tn = (tile < 15) ? (tile + 1) : 15;
            const float* xr = x + (base + tn * 16 + nl) * 20;
            if (quad < 2) {
                xp0 = *(const float4*)(xr + quad * 8);
                xp1 = *(const float4*)(xr + quad * 8 + 4);
            } else if (quad == 2) {
                xp0 = *(const float4*)(xr + 16);
            }
        }

        F8 A1h, A1l;
        split_pack(xk, A1h.u, A1l.u);

        floatx4 acc1[4];
#pragma unroll
        for (int T = 0; T < 4; ++T) acc1[T] = (floatx4){b0v[T], b0v[T], b0v[T], b0v[T]};
#pragma unroll
        for (int T = 0; T < 4; ++T) {
            acc1[T] = __builtin_amdgcn_mfma_f32_16x16x32_bf16(A1h.v, B1h[T].v, acc1[T], 0, 0, 0);
            acc1[T] = __builtin_amdgcn_mfma_f32_16x16x32_bf16(A1l.v, B1h[T].v, acc1[T], 0, 0, 0);
            acc1[T] = __builtin_amdgcn_mfma_f32_16x16x32_bf16(A1h.v, B1l[T].v, acc1[T], 0, 0, 0);
        }

        // relu + transpose (C-layout -> [tau][e])
#pragma unroll
        for (int T = 0; T < 4; ++T)
#pragma unroll
            for (int reg = 0; reg < 4; ++reg)
                tA[wv][(quad * 4 + reg) * LDW2 + T * 16 + nl] = fmaxf(acc1[T][reg], 0.f);
        __builtin_amdgcn_wave_barrier();

        F8 A2h[2], A2l[2];
#pragma unroll
        for (int KH = 0; KH < 2; ++KH) {
            float xe[8];
#pragma unroll
            for (int e = 0; e < 8; ++e)
                xe[e] = tA[wv][nl * LDW2 + KH * 32 + quad * 8 + e];
            split_pack(xe, A2h[KH].u, A2l[KH].u);
        }

        floatx4 acc2[4];
#pragma unroll
        for (int T = 0; T < 4; ++T) acc2[T] = (floatx4){bfv[T], bfv[T], bfv[T], bfv[T]};
#pragma unroll
        for (int T = 0; T < 4; ++T)
#pragma unroll
            for (int KH = 0; KH < 2; ++KH) {
                acc2[T] = __builtin_amdgcn_mfma_f32_16x16x32_bf16(A2h[KH].v, B2h[T][KH].v, acc2[T], 0, 0, 0);
                acc2[T] = __builtin_amdgcn_mfma_f32_16x16x32_bf16(A2l[KH].v, B2h[T][KH].v, acc2[T], 0, 0, 0);
                acc2[T] = __builtin_amdgcn_mfma_f32_16x16x32_bf16(A2h[KH].v, B2l[T][KH].v, acc2[T], 0, 0, 0);
            }

        // gpre transpose -> [tau][gate] rows in LDS
#pragma unroll
        for (int T = 0; T < 4; ++T)
#pragma unroll
            for (int reg = 0; reg < 4; ++reg)
                tB[wv][(quad * 4 + reg) * LDW2 + T * 16 + nl] = acc2[T][reg];
        __builtin_amdgcn_wave_barrier();

        // pack step-pairs (2tp, 2tp+1) to f16x2 (RNE); per-lane-contiguous 32B store
        {
            B8 r;
#pragma unroll
            for (int tp = 0; tp < 8; ++tp) {
                float a0 = tB[wv][(2 * tp) * LDW2 + j];
                float a1 = tB[wv][(2 * tp + 1) * LDW2 + j];
                H2 pk;
                pk.h[0] = (_Float16)a0;   // v_cvt_f16_f32 (RNE)
                pk.h[1] = (_Float16)a1;
                r.d[tp] = pk.u;
            }
            uint32_t* gp = gph + ((size_t)(blockIdx.x * 4 + wv) * 16 + tile) * 512 + j * 8;
            *(uint4*)(gp)     = r.q[0];
            *(uint4*)(gp + 4) = r.q[1];
        }
        __builtin_amdgcn_wave_barrier();   // protect tA/tB reuse next tile
    }
}

// ===================== K2: serial scan + epilogue =====================
// R11-exact: pre-scaled gpre -> exp2 direct; C = -2log2e*c carried (scale folded
// into g-gate amul/aadd); 2-accumulator asm matvec; dwordx4 gph refills.
__global__ __launch_bounds__(256, 4)
void lstm_scan(const uint32_t* __restrict__ gph,
               const float* __restrict__ x,
               const float* __restrict__ W0, const float* __restrict__ b0,
               const float* __restrict__ Wf,
               const float* __restrict__ Wb, const float* __restrict__ bb,
               const float* __restrict__ W1, const float* __restrict__ b1,
               const float* __restrict__ W2, const float* __restrict__ b2,
               const float* __restrict__ W3, const float* __restrict__ b3,
               float* __restrict__ out)
{
    __shared__ __align__(16) float xh_sh[4][64];
    __shared__ __align__(16) float h_sh[4][48];   // [0:16) hf, [16:32) hb, [32:48) l2

    const int wv   = threadIdx.x >> 6;
    const int j    = threadIdx.x & 63;
    const int b    = blockIdx.x * 4 + wv;
    const int nl   = j & 15;
    const int quad = j >> 4;

    int rot1 = __builtin_amdgcn_mov_dpp(j, 0x121, 0xf, 0xf, false);
    const bool plus = ((rot1 & 15) == ((nl + 1) & 15));

    // recurrent weights, pre-scaled by the gate's exp2 factor (matches K1's gpre scale)
    const float sj = (quad == 1) ? (-2.f * LOG2E) : (-LOG2E);
    float wfhp[16];
#pragma unroll
    for (int s = 0; s < 16; ++s) {
        const int srcq = plus ? ((nl + s) & 15) : ((nl + 16 - s) & 15);
        wfhp[s] = Wf[(64 + srcq) * 64 + j] * sj;
    }

    // scan-loop activation constants:
    //  q0,2,3: a = sigmoid = rcp(1+e)              -> amul=1, aadd=0
    //  q1:     a = -2log2e * tanh(g) = amul*y+aadd -> amul=-4log2e, aadd=+2log2e
    const float amul = (quad == 1) ? (-4.f * LOG2E) : 1.f;
    const float aadd = (quad == 1) ? ( 2.f * LOG2E) : 0.f;

    // epilogue (bwd step) constants — original unscaled forms
    const float gmulE = (quad == 1) ? -2.f : -1.f;
    const float amulE = (quad == 1) ? 2.f : 1.f;
    const float aaddE = (quad == 1) ? -1.f : 0.f;

    // bpermute byte-addresses for gathering i/g/f/o of unit nl (hoisted)
    const int adr_i = 4 * nl;
    const int adr_g = 4 * nl + 64;
    const int adr_f = 4 * nl + 128;
    const int adr_o = 4 * nl + 192;

    float C = 0.f, hh = 0.f;   // C = -2log2e * c
    const uint32_t* gb = gph + (size_t)b * 8192;   // 16 blocks x 512 dwords

    // one LSTM step given pre-scaled gate pre-activation G.
    // 2-accumulator chain: dependency distance 2 covers VALU->DPP wait states
    // (R12's single-acc chain exposed latency: VALUBusy 73->62, -8.4us).
#define STEPG(G)                                                               \
    {                                                                          \
        float v0 = (G), v1;                                                    \
        asm volatile(                                                          \
            "v_fmac_f32 %0, %2, %3\n\t"                                        \
            "s_nop 1\n\t"                                                      \
            "v_mul_f32_dpp %1, %2, %4 row_ror:1 row_mask:0xf bank_mask:0xf\n\t"  \
            "v_fmac_f32_dpp %0, %2, %5 row_ror:2 row_mask:0xf bank_mask:0xf\n\t" \
            "v_fmac_f32_dpp %1, %2, %6 row_ror:3 row_mask:0xf bank_mask:0xf\n\t" \
            "v_fmac_f32_dpp %0, %2, %7 row_ror:4 row_mask:0xf bank_mask:0xf\n\t" \
            "v_fmac_f32_dpp %1, %2, %8 row_ror:5 row_mask:0xf bank_mask:0xf\n\t" \
            "v_fmac_f32_dpp %0, %2, %9 row_ror:6 row_mask:0xf bank_mask:0xf\n\t" \
            "v_fmac_f32_dpp %1, %2, %10 row_ror:7 row_mask:0xf bank_mask:0xf\n\t" \
            "v_fmac_f32_dpp %0, %2, %11 row_ror:8 row_mask:0xf bank_mask:0xf\n\t" \
            "v_fmac_f32_dpp %1, %2, %12 row_ror:9 row_mask:0xf bank_mask:0xf\n\t" \
            "v_fmac_f32_dpp %0, %2, %13 row_ror:10 row_mask:0xf bank_mask:0xf\n\t" \
            "v_fmac_f32_dpp %1, %2, %14 row_ror:11 row_mask:0xf bank_mask:0xf\n\t" \
            "v_fmac_f32_dpp %0, %2, %15 row_ror:12 row_mask:0xf bank_mask:0xf\n\t" \
            "v_fmac_f32_dpp %1, %2, %16 row_ror:13 row_mask:0xf bank_mask:0xf\n\t" \
            "v_fmac_f32_dpp %0, %2, %17 row_ror:14 row_mask:0xf bank_mask:0xf\n\t" \
            "v_fmac_f32_dpp %1, %2, %18 row_ror:15 row_mask:0xf bank_mask:0xf"   \
            : "+&v"(v0), "=&v"(v1)                                             \
            : "v"(hh),                                                         \
              "v"(wfhp[0]),  "v"(wfhp[1]),  "v"(wfhp[2]),  "v"(wfhp[3]),       \
              "v"(wfhp[4]),  "v"(wfhp[5]),  "v"(wfhp[6]),  "v"(wfhp[7]),       \
              "v"(wfhp[8]),  "v"(wfhp[9]),  "v"(wfhp[10]), "v"(wfhp[11]),      \
              "v"(wfhp[12]), "v"(wfhp[13]), "v"(wfhp[14]), "v"(wfhp[15]));     \
        float e = __builtin_amdgcn_exp2f(v0 + v1);                             \
        float y = __builtin_amdgcn_rcpf(1.f + e);                              \
        float a = fmaf(y, amul, aadd);                                         \
        int ab = __float_as_int(a);                                            \
        float ai = __int_as_float(__builtin_amdgcn_ds_bpermute(adr_i, ab));    \
        float ag = __int_as_float(__builtin_amdgcn_ds_bpermute(adr_g, ab));    \
        float af = __int_as_float(__builtin_amdgcn_ds_bpermute(adr_f, ab));    \
        float ao = __int_as_float(__builtin_amdgcn_ds_bpermute(adr_o, ab));    \
        C = fmaf(af, C, ai * ag);                                              \
        float e2 = __builtin_amdgcn_exp2f(C);                                  \
        float th = fmaf(__builtin_amdgcn_rcpf(1.f + e2), 2.f, -1.f);           \
        hh = ao * th;                                                          \
    }

    // parity double-buffered blocks: 16 blocks x 8 dwords (= 16 steps each)
    B8 bufA, bufB;
    bufA.q[0] = *(const uint4*)(gb + j * 8);
    bufA.q[1] = *(const uint4*)(gb + j * 8 + 4);
    bufB.q[0] = *(const uint4*)(gb + 512 + j * 8);
    bufB.q[1] = *(const uint4*)(gb + 512 + j * 8 + 4);

#pragma unroll 1
    for (int blk = 0; blk < 16; blk += 2) {
#pragma unroll
        for (int p = 0; p < 8; ++p) {
            H2 u; u.u = bufA.d[p];
            float g0 = (float)u.h[0];
            float g1 = (float)u.h[1];
            STEPG(g0)
            STEPG(g1)
        }
        {
            int nb = blk + 2; nb = (nb > 15) ? 15 : nb;   // uniform clamp
            bufA.q[0] = *(const uint4*)(gb + nb * 512 + j * 8);
            bufA.q[1] = *(const uint4*)(gb + nb * 512 + j * 8 + 4);
        }
#pragma unroll
        for (int p = 0; p < 8; ++p) {
            H2 u; u.u = bufB.d[p];
            float g0 = (float)u.h[0];
            float g1 = (float)u.h[1];
            STEPG(g0)
            STEPG(g1)
        }
        {
            int nb = blk + 3; nb = (nb > 15) ? 15 : nb;
            bufB.q[0] = *(const uint4*)(gb + nb * 512 + j * 8);
            bufB.q[1] = *(const uint4*)(gb + nb * 512 + j * 8 + 4);
        }
    }
#undef STEPG

    // epilogue: recompute xh[255] exactly from x
    {
        const float* xr = x + (size_t)b * (256 * 20) + 255 * 20;
        float s = b0[j];
#pragma unroll
        for (int k = 0; k < 20; ++k) s = fmaf(xr[k], W0[k * 64 + j], s);
        xh_sh[wv][j] = fmaxf(s, 0.f);
        if (j < 16) h_sh[wv][j] = hh;
    }
    __builtin_amdgcn_wave_barrier();

    // bwd LSTM single step from zero state (original constants)
    {
        float u0 = bb[j], u1 = 0.f, u2 = 0.f, u3 = 0.f;
        const float* xr = xh_sh[wv];
#pragma unroll
        for (int k4 = 0; k4 < 16; ++k4) {
            u0 = fmaf(xr[4 * k4 + 0], Wb[(4 * k4 + 0) * 64 + j], u0);
            u1 = fmaf(xr[4 * k4 + 1], Wb[(4 * k4 + 1) * 64 + j], u1);
            u2 = fmaf(xr[4 * k4 + 2], Wb[(4 * k4 + 2) * 64 + j], u2);
            u3 = fmaf(xr[4 * k4 + 3], Wb[(4 * k4 + 3) * 64 + j], u3);
        }
        float gated = (u0 + u1) + (u2 + u3);
        float e = __expf(gmulE * gated);
        float y = __fdividef(1.f, 1.f + e);
        float a = fmaf(y, amulE, aaddE);
        float ai = __shfl(a, nl, 64);
        float ag = __shfl(a, nl + 16, 64);
        float ao = __shfl(a, nl + 48, 64);
        float cb = ai * ag;
        float hb = ao * tanh_fast(cb);
        __builtin_amdgcn_wave_barrier();
        if (j < 16) h_sh[wv][16 + j] = hb;
        __builtin_amdgcn_wave_barrier();
    }

    // head MLP
    {
        float u0 = b1[j], u1 = 0.f, u2 = 0.f, u3 = 0.f;
        const float4* hs = (const float4*)h_sh[wv];
#pragma unroll
        for (int k4 = 0; k4 < 8; ++k4) {
            float4 v = hs[k4];
            u0 = fmaf(v.x, W1[(4 * k4 + 0) * 64 + j], u0);
            u1 = fmaf(v.y, W1[(4 * k4 + 1) * 64 + j], u1);
            u2 = fmaf(v.z, W1[(4 * k4 + 2) * 64 + j], u2);
            u3 = fmaf(v.w, W1[(4 * k4 + 3) * 64 + j], u3);
        }
        float l1 = fmaxf((u0 + u1) + (u2 + u3), 0.f);
        __builtin_amdgcn_wave_barrier();
        xh_sh[wv][j] = l1;
        __builtin_amdgcn_wave_barrier();

        if (j < 16) {
            float v0 = b2[j], v1 = 0.f, v2 = 0.f, v3 = 0.f;
            const float4* ls = (const float4*)xh_sh[wv];
#pragma unroll
            for (int k4 = 0; k4 < 16; ++k4) {
                float4 v = ls[k4];
                v0 = fmaf(v.x, W2[(4 * k4 + 0) * 16 + j], v0);
                v1 = fmaf(v.y, W2[(4 * k4 + 1) * 16 + j], v1);
                v2 = fmaf(v.z, W2[(4 * k4 + 2) * 16 + j], v2);
                v3 = fmaf(v.w, W2[(4 * k4 + 3) * 16 + j], v3);
            }
            h_sh[wv][32 + j] = fmaxf((v0 + v1) + (v2 + v3), 0.f);
        }
        __builtin_amdgcn_wave_barrier();

        if (j < 2) {
            float o = b3[j];
#pragma unroll
            for (int k = 0; k < 16; ++k)
                o = fmaf(h_sh[wv][32 + k], W3[k * 2 + j], o);
            out[b * 2 + j] = o;
        }
    }
}

// ===================== fallback: unchanged R4 fused kernel =====================
__global__ __launch_bounds__(64, 2)
void bilstm_fused_r4(const float* __restrict__ x,
                     const float* __restrict__ W0, const float* __restrict__ b0,
                     const float* __restrict__ Wf, const float* __restrict__ bf,
                     const float* __restrict__ Wb, const float* __restrict__ bb,
                     const float* __restrict__ W1, const float* __restrict__ b1,
                     const float* __restrict__ W2, const float* __restrict__ b2,
                     const float* __restrict__ W3, const float* __restrict__ b3,
                     float* __restrict__ out)
{
    __shared__ __align__(16) float lds_xh[16 * LDW];
    __shared__ __align__(16) float lds_g [16 * LDW];
    __shared__ __align__(16) float h_sh[48];

    const int j    = threadIdx.x;
    const int b    = blockIdx.x;
    const int nl   = j & 15;
    const int quad = j >> 4;

    int rot1 = __builtin_amdgcn_mov_dpp(j, 0x121, 0xf, 0xf, false);
    const bool plus = ((rot1 & 15) == ((nl + 1) & 15));

    float wfhp[16];
#pragma unroll
    for (int s = 0; s < 16; ++s) {
        const int srcq = plus ? ((nl + s) & 15) : ((nl + 16 - s) & 15);
        wfhp[s] = Wf[(64 + srcq) * 64 + j];
    }

    F8 B1h[4], B1l[4];
#pragma unroll
    for (int T = 0; T < 4; ++T) {
        float w[8];
#pragma unroll
        for (int e = 0; e < 8; ++e) {
            int k = quad * 8 + e;
            w[e] = (k < 20) ? W0[k * 64 + T * 16 + nl] : 0.f;
        }
        split_pack(w, B1h[T].u, B1l[T].u);
    }
    F8 B2h[4][2], B2l[4][2];
#pragma unroll
    for (int T = 0; T < 4; ++T)
#pragma unroll
        for (int KH = 0; KH < 2; ++KH) {
            float w[8];
#pragma unroll
            for (int e = 0; e < 8; ++e) {
                int k = KH * 32 + quad * 8 + e;
                w[e] = Wf[k * 64 + T * 16 + nl];
            }
            split_pack(w, B2h[T][KH].u, B2l[T][KH].u);
        }

    float b0v[4], bfv[4];
#pragma unroll
    for (int T = 0; T < 4; ++T) {
        b0v[T] = b0[T * 16 + nl];
        bfv[T] = bf[T * 16 + nl];
    }

    const float gmul  = (quad == 1) ? -2.f : -1.f;
    const float gbias = (quad == 2) ? 1.f : 0.f;
    const float amul  = (quad == 1) ? 2.f : 1.f;
    const float aadd  = (quad == 1) ? -1.f : 0.f;
    const bool  b0sel = (quad & 1) != 0;
    const bool  b1sel = (quad & 2) != 0;

    float c = 0.f, hh = 0.f;
    const float* xb = x + (size_t)b * (256 * 20);

#pragma unroll 1
    for (int ch = 0; ch < 16; ++ch) {
        const int t0 = ch * 16;
        const float* xrow = xb + (size_t)(t0 + nl) * 20;
        float xk[8];
#pragma unroll
        for (int e = 0; e < 8; ++e) {
            int k = quad * 8 + e;
            xk[e] = (k < 20) ? xrow[k] : 0.f;
        }
        F8 A1h, A1l;
        split_pack(xk, A1h.u, A1l.u);

        floatx4 acc1[4];
#pragma unroll
        for (int T = 0; T < 4; ++T) acc1[T] = (floatx4){b0v[T], b0v[T], b0v[T], b0v[T]};
#pragma unroll
        for (int T = 0; T < 4; ++T) {
            acc1[T] = __builtin_amdgcn_mfma_f32_16x16x32_bf16(A1h.v, B1h[T].v, acc1[T], 0, 0, 0);
            acc1[T] = __builtin_amdgcn_mfma_f32_16x16x32_bf16(A1l.v, B1h[T].v, acc1[T], 0, 0, 0);
            acc1[T] = __builtin_amdgcn_mfma_f32_16x16x32_bf16(A1h.v, B1l[T].v, acc1[T], 0, 0, 0);
        }
#pragma unroll
        for (int T = 0; T < 4; ++T)
#pragma unroll
            for (int reg = 0; reg < 4; ++reg)
                lds_xh[(quad * 4 + reg) * LDW + T * 16 + nl] = fmaxf(acc1[T][reg], 0.f);
        __builtin_amdgcn_wave_barrier();

        F8 A2h[2], A2l[2];
#pragma unroll
        for (int KH = 0; KH < 2; ++KH) {
            float xe[8];
#pragma unroll
            for (int e = 0; e < 8; ++e)
                xe[e] = lds_xh[nl * LDW + KH * 32 + quad * 8 + e];
            split_pack(xe, A2h[KH].u, A2l[KH].u);
        }

        floatx4 acc2[4];
#pragma unroll
        for (int T = 0; T < 4; ++T) acc2[T] = (floatx4){bfv[T], bfv[T], bfv[T], bfv[T]};
#pragma unroll
        for (int T = 0; T < 4; ++T)
#pragma unroll
            for (int KH = 0; KH < 2; ++KH) {
                acc2[T] = __builtin_amdgcn_mfma_f32_16x16x32_bf16(A2h[KH].v, B2h[T][KH].v, acc2[T], 0, 0, 0);
                acc2[T] = __builtin_amdgcn_mfma_f32_16x16x32_bf16(A2l[KH].v, B2h[T][KH].v, acc2[T], 0, 0, 0);
                acc2[T] = __builtin_amdgcn_mfma_f32_16x16x32_bf16(A2h[KH].v, B2l[T][KH].v, acc2[T], 0, 0, 0);
            }
#pragma unroll
        for (int T = 0; T < 4; ++T)
#pragma unroll
            for (int reg = 0; reg < 4; ++reg)
                lds_g[(quad * 4 + reg) * LDW + T * 16 + nl] = acc2[T][reg];
        __builtin_amdgcn_wave_barrier();

        float gcur = lds_g[j];
#pragma unroll
        for (int tau = 0; tau < 16; ++tau) {
            float gnext = lds_g[((tau < 15) ? (tau + 1) : 15) * LDW + j];
            float v0 = hh * wfhp[0];
            float v1 = ROT(hh, 1) * wfhp[1];
            float v2 = ROT(hh, 2) * wfhp[2];
            float v3 = ROT(hh, 3) * wfhp[3];
            v0 = fmaf(ROT(hh, 4),  wfhp[4],  v0);
            v1 = fmaf(ROT(hh, 5),  wfhp[5],  v1);
            v2 = fmaf(ROT(hh, 6),  wfhp[6],  v2);
            v3 = fmaf(ROT(hh, 7),  wfhp[7],  v3);
            v0 = fmaf(ROT(hh, 8),  wfhp[8],  v0);
            v1 = fmaf(ROT(hh, 9),  wfhp[9],  v1);
            v2 = fmaf(ROT(hh, 10), wfhp[10], v2);
            v3 = fmaf(ROT(hh, 11), wfhp[11], v3);
            v0 = fmaf(ROT(hh, 12), wfhp[12], v0);
            v1 = fmaf(ROT(hh, 13), wfhp[13], v1);
            v2 = fmaf(ROT(hh, 14), wfhp[14], v2);
            v3 = fmaf(ROT(hh, 15), wfhp[15], v3);
            float gated = gcur + ((v0 + v1) + (v2 + v3));

            float e = __expf(gmul * (gated + gbias));
            float y = __fdividef(1.f, 1.f + e);
            float a = fmaf(y, amul, aadd);

            float d1 = __shfl_xor(a, 16);
            float d2 = __shfl_xor(a, 32);
            float d3 = __shfl_xor(a, 48);
            float lo  = b0sel ? d1 : a;
            float hi  = b0sel ? d3 : d2;
            float lo1 = b0sel ? a  : d1;
            float hi1 = b0sel ? d2 : d3;
            float ai = b1sel ? hi  : lo;
            float ag = b1sel ? hi1 : lo1;
            float af = b1sel ? lo  : hi;
            float ao = b1sel ? lo1 : hi1;

            c  = fmaf(af, c, ai * ag);
            hh = ao * tanh_fast(c);
            gcur = gnext;
        }
    }

    if (j < 16) h_sh[j] = hh;
    __builtin_amdgcn_wave_barrier();

    {
        float u0 = bb[j], u1 = 0.f, u2 = 0.f, u3 = 0.f;
        const float* xr = &lds_xh[15 * LDW];
#pragma unroll
        for (int k4 = 0; k4 < 16; ++k4) {
            u0 = fmaf(xr[4 * k4 + 0], Wb[(4 * k4 + 0) * 64 + j], u0);
            u1 = fmaf(xr[4 * k4 + 1], Wb[(4 * k4 + 1) * 64 + j], u1);
            u2 = fmaf(xr[4 * k4 + 2], Wb[(4 * k4 + 2) * 64 + j], u2);
            u3 = fmaf(xr[4 * k4 + 3], Wb[(4 * k4 + 3) * 64 + j], u3);
        }
        float gated = (u0 + u1) + (u2 + u3);
        float e = __expf(gmul * gated);
        float y = __fdividef(1.f, 1.f + e);
        float a = fmaf(y, amul, aadd);
        float ai = __shfl(a, nl, 64);
        float ag = __shfl(a, nl + 16, 64);
        float ao = __shfl(a, nl + 48, 64);
        float cb = ai * ag;
        float hb = ao * tanh_fast(cb);
        __builtin_amdgcn_wave_barrier();
        if (j < 16) h_sh[16 + j] = hb;
        __builtin_amdgcn_wave_barrier();
    }

    {
        float u0 = b1[j], u1 = 0.f, u2 = 0.f, u3 = 0.f;
        const float4* hs = (const float4*)h_sh;
#pragma unroll
        for (int k4 = 0; k4 < 8; ++k4) {
            float4 v = hs[k4];
            u0 = fmaf(v.x, W1[(4 * k4 + 0) * 64 + j], u0);
            u1 = fmaf(v.y, W1[(4 * k4 + 1) * 64 + j], u1);
            u2 = fmaf(v.z, W1[(4 * k4 + 2) * 64 + j], u2);
            u3 = fmaf(v.w, W1[(4 * k4 + 3) * 64 + j], u3);
        }
        float l1 = fmaxf((u0 + u1) + (u2 + u3), 0.f);
        __builtin_amdgcn_wave_barrier();
        lds_g[j] = l1;
        __builtin_amdgcn_wave_barrier();

        if (j < 16) {
            float v0 = b2[j], v1 = 0.f, v2 = 0.f, v3 = 0.f;
            const float4* ls = (const float4*)lds_g;
#pragma unroll
            for (int k4 = 0; k4 < 16; ++k4) {
                float4 v = ls[k4];
                v0 = fmaf(v.x, W2[(4 * k4 + 0) * 16 + j], v0);
                v1 = fmaf(v.y, W2[(4 * k4 + 1) * 16 + j], v1);
                v2 = fmaf(v.z, W2[(4 * k4 + 2) * 16 + j], v2);
                v3 = fmaf(v.w, W2[(4 * k4 + 3) * 16 + j], v3);
            }
            h_sh[32 + j] = fmaxf((v0 + v1) + (v2 + v3), 0.f);
        }
        __builtin_amdgcn_wave_barrier();

        if (j < 2) {
            float o = b3[j];
#pragma unroll
            for (int k = 0; k < 16; ++k)
                o = fmaf(h_sh[32 + k], W3[k * 2 + j], o);
            out[b * 2 + j] = o;
        }
    }
}

extern "C" void kernel_launch(void* const* d_in, const int* in_sizes, int n_in,
                              void* d_out, int out_size, void* d_ws, size_t ws_size,
                              hipStream_t stream) {
    const float* x  = (const float*)d_in[0];
    const float* W0 = (const float*)d_in[1];
    const float* b0 = (const float*)d_in[2];
    const float* Wf = (const float*)d_in[3];
    const float* bf = (const float*)d_in[4];
    const float* Wb = (const float*)d_in[5];
    const float* bb = (const float*)d_in[6];
    const float* W1 = (const float*)d_in[7];
    const float* b1 = (const float*)d_in[8];
    const float* W2 = (const float*)d_in[9];
    const float* b2 = (const float*)d_in[10];
    const float* W3 = (const float*)d_in[11];
    const float* b3 = (const float*)d_in[12];
    float* outp = (float*)d_out;

    const size_t need = (size_t)4096 * 128 * 64 * sizeof(uint32_t);  // 134 MB (f16 pairs)
    if (ws_size >= need) {
        uint32_t* gph = (uint32_t*)d_ws;
        hipLaunchKernelGGL(gpre_gemm, dim3(1024), dim3(256), 0, stream,
                           x, W0, b0, Wf, bf, gph);
        hipLaunchKernelGGL(lstm_scan, dim3(1024), dim3(256), 0, stream,
                           gph, x, W0, b0, Wf, Wb, bb, W1, b1, W2, b2, W3, b3, outp);
    } else {
        hipLaunchKernelGGL(bilstm_fused_r4, dim3(4096), dim3(64), 0, stream,
                           x, W0, b0, Wf, bf, Wb, bb, W1, b1, W2, b2, W3, b3, outp);
    }
}